// Round 5
// baseline (235.263 us; speedup 1.0000x reference)
//
#include <hip/hip_runtime.h>
#include <stdint.h>

typedef __attribute__((ext_vector_type(4))) float fv4;
typedef __attribute__((ext_vector_type(4))) short sv4;
typedef __attribute__((ext_vector_type(8))) short sv8;

#define SCHUNK 2048
#define FPB 64      // facets per block in k_main
#define SMAX 192    // staged samples per chunk
#define PZF 100     // Zf (fp32 accum) row pitch, floats
#define PZB 108     // Zb (bf16 GEMM input) row pitch, shorts

static __device__ __forceinline__ short f2bf(float f) {
  union { float f; unsigned u; } v; v.f = f;
  unsigned u = v.u;
  u += 0x7fffu + ((u >> 16) & 1u);   // RNE to bf16
  return (short)(u >> 16);
}

// ---------------- scan: offsets from num_texture (R1-validated) ----------------
__global__ __launch_bounds__(256) void scan1(const int* __restrict__ num, int nf,
                                             int* __restrict__ bsum) {
  __shared__ int sd[256];
  int b = blockIdx.x, tid = threadIdx.x;
  int base = b * SCHUNK + tid * 8;
  int s = 0;
#pragma unroll
  for (int j = 0; j < 8; ++j) { int i = base + j; if (i < nf) s += num[i]; }
  sd[tid] = s; __syncthreads();
  for (int st = 128; st > 0; st >>= 1) {
    if (tid < st) sd[tid] += sd[tid + st];
    __syncthreads();
  }
  if (tid == 0) bsum[b] = sd[0];
}

__global__ __launch_bounds__(256) void scan2(int* __restrict__ bsum, int nb) {
  __shared__ int sd[256];
  int tid = threadIdx.x;
  int v = (tid < nb) ? bsum[tid] : 0;
  sd[tid] = v; __syncthreads();
  for (int off = 1; off < 256; off <<= 1) {
    int t = (tid >= off) ? sd[tid - off] : 0;
    __syncthreads();
    sd[tid] += t;
    __syncthreads();
  }
  if (tid < nb) bsum[tid] = sd[tid] - v;   // exclusive prefix
}

__global__ __launch_bounds__(256) void scan3(const int* __restrict__ num, int nf,
                                             const int* __restrict__ bsum,
                                             int* __restrict__ offsets) {
  __shared__ int sc_[256];
  int b = blockIdx.x, tid = threadIdx.x;
  int base = b * SCHUNK + tid * 8;
  int loc[8]; int s = 0;
#pragma unroll
  for (int j = 0; j < 8; ++j) {
    loc[j] = (base + j < nf) ? num[base + j] : 0;
    s += loc[j];
  }
  sc_[tid] = s; __syncthreads();
  for (int off = 1; off < 256; off <<= 1) {
    int t = (tid >= off) ? sc_[tid - off] : 0;
    __syncthreads();
    sc_[tid] += t;
    __syncthreads();
  }
  int run = bsum[b] + sc_[tid] - s;
#pragma unroll
  for (int j = 0; j < 8; ++j) {
    if (base + j < nf) offsets[base + j] = run;
    run += loc[j];
  }
  if (b == gridDim.x - 1 && tid == 255) offsets[nf] = run;
}

// ---------------- main: stage->fold(LDS)->GEMM->avg+bias+relu + stats ----------------
// Zf[f, k*32+c] = sum_{s in facet f} x[s,c]*b[s,k]   (fp32 accum in LDS)
// out[f,o] = relu( (1/n_f) * sum_{ck} bf16(Zf)[f,ck]*W2[o,ck] + bias[o] )
__global__ __launch_bounds__(256) void k_main(
    const float* __restrict__ x, const float* __restrict__ bary,
    const float* __restrict__ W, const float* __restrict__ bias,
    const int* __restrict__ offsets, float* __restrict__ out,
    float* __restrict__ partials, int nf, int nblk)
{
  __shared__ float Zf[FPB * PZF];      // 25600 B; aliased as float yt[64*33] after GEMM
  __shared__ float Xs[SMAX * 32];      // 24576 B; aliased as short Zb[64*PZB] for GEMM
  __shared__ float Bs[SMAX * 3];       // 2304 B
  __shared__ short W2[32 * PZB];       // 6912 B; aliased as float red[512] at finalize
  __shared__ int off_s[FPB + 1];

  const int tid = threadIdx.x;
  const int f0 = blockIdx.x * FPB;

  // stage W2[o*PZB + k*32 + c] = bf16(W[o*96 + c*3 + k])   (R1-validated)
  for (int idx = tid; idx < 3072; idx += 256) {
    int o = idx / 96;
    int ck = idx - o * 96;
    int k = ck >> 5, c = ck & 31;
    W2[o * PZB + ck] = f2bf(W[o * 96 + c * 3 + k]);
  }
  for (int i = tid; i < FPB + 1; i += 256) {
    int f = f0 + i; if (f > nf) f = nf;
    off_s[i] = offsets[f];
  }
  for (int idx = tid; idx < FPB * PZF; idx += 256) Zf[idx] = 0.f;
  __syncthreads();

  const int s_lo = off_s[0];
  const int s_hi = off_s[FPB];

  // ---- chunked: bulk-stage samples to LDS, then fold from LDS ----
  for (int clo = s_lo; clo < s_hi; clo += SMAX) {
    const int cnt = (s_hi - clo < SMAX) ? (s_hi - clo) : SMAX;
    const int chi = clo + cnt;

    // stage x rows: cnt*8 fv4 loads, independent + coalesced
    for (int i = tid; i < cnt * 8; i += 256)
      *(fv4*)&Xs[4 * i] = *(const fv4*)(x + (size_t)clo * 32 + 4 * i);
    // stage bary
    for (int i = tid; i < cnt * 3; i += 256)
      Bs[i] = bary[(size_t)clo * 3 + i];
    __syncthreads();

    // fold (R4-validated shape, LDS-sourced): one task per (facet, channel)
    for (int idx = tid; idx < FPB * 32; idx += 256) {
      int fl = idx >> 5, c = idx & 31;
      int st = off_s[fl], en = off_s[fl + 1];
      int a = st > clo ? st : clo;
      int b = en < chi ? en : chi;
      float z0 = 0.f, z1 = 0.f, z2 = 0.f;
      for (int t = a; t < b; ++t) {
        int tl = t - clo;
        float xv = Xs[tl * 32 + c];
        z0 += xv * Bs[tl * 3 + 0];
        z1 += xv * Bs[tl * 3 + 1];
        z2 += xv * Bs[tl * 3 + 2];
      }
      if (b > a) {
        float* zp = &Zf[fl * PZF + c];
        zp[0]  += z0;
        zp[32] += z1;
        zp[64] += z2;
      }
    }
    __syncthreads();
  }

  // ---- convert Zf -> bf16 Zb (staging buffer is dead now) ----
  short* Zb = (short*)Xs;
  for (int idx = tid; idx < FPB * 32; idx += 256) {
    int fl = idx >> 5, c = idx & 31;
    const float* zp = &Zf[fl * PZF + c];
    short* zb = &Zb[fl * PZB + c];
    zb[0]  = f2bf(zp[0]);
    zb[32] = f2bf(zp[32]);
    zb[64] = f2bf(zp[64]);
  }
  __syncthreads();

  // ---- GEMM: M=64 (facets), N=32, K=96; 4 waves x 1 M-tile x 2 N-tiles ----
  const int lane = tid & 63;
  const int wv = tid >> 6;
  const int rowl = lane & 15;
  const int grp = lane >> 4;

  fv4 acc[2];
  acc[0] = (fv4){0.f, 0.f, 0.f, 0.f};
  acc[1] = (fv4){0.f, 0.f, 0.f, 0.f};

#pragma unroll
  for (int kb = 0; kb < 3; ++kb) {
    const int cko = kb * 32 + grp * 4;
    sv8 bfr[2];
#pragma unroll
    for (int n = 0; n < 2; ++n) {
      const short* wr = &W2[(n * 16 + rowl) * PZB + cko];
      sv4 lo = *(const sv4*)(wr);
      sv4 hi = *(const sv4*)(wr + 16);
#pragma unroll
      for (int j = 0; j < 4; ++j) { bfr[n][j] = lo[j]; bfr[n][4 + j] = hi[j]; }
    }
    const short* zr = &Zb[(wv * 16 + rowl) * PZB + cko];
    sv4 lo = *(const sv4*)(zr);
    sv4 hi = *(const sv4*)(zr + 16);
    sv8 afr;
#pragma unroll
    for (int j = 0; j < 4; ++j) { afr[j] = lo[j]; afr[4 + j] = hi[j]; }
    acc[0] = __builtin_amdgcn_mfma_f32_16x16x32_bf16(afr, bfr[0], acc[0], 0, 0, 0);
    acc[1] = __builtin_amdgcn_mfma_f32_16x16x32_bf16(afr, bfr[1], acc[1], 0, 0, 0);
  }

  // ---- y-tile to LDS with R1-validated C-write formula (alias over Zf) ----
  float* yt = Zf;               // 64 x 33 floats = 8448 B
#pragma unroll
  for (int n = 0; n < 2; ++n)
#pragma unroll
    for (int r = 0; r < 4; ++r)
      yt[(wv * 16 + grp * 4 + r) * 33 + n * 16 + rowl] = acc[n][r];
  __syncthreads();

  // ---- finalize with R4-validated pattern: avg + bias + relu, out, stats ----
  const int o_ep = tid & 31;
  const int g_ep = tid >> 5;
  float bo = bias[o_ep];
  float s1 = 0.f, s2 = 0.f;
#pragma unroll
  for (int i = 0; i < 8; ++i) {
    int fl = i * 8 + g_ep;
    int f = f0 + fl;
    if (f < nf) {
      int nm = off_s[fl + 1] - off_s[fl];
      float v = yt[fl * 33 + o_ep] / (float)(nm > 1 ? nm : 1) + bo;
      v = fmaxf(v, 0.f);
      out[f * 32 + o_ep] = v;
      s1 += v; s2 += v * v;
    }
  }
  __syncthreads();              // all W2/yt reads done; safe to alias red
  float* red = (float*)W2;      // 512 floats = 2048 B
  red[tid] = s1;
  red[256 + tid] = s2;
  __syncthreads();
  if (tid < 32) {
    float a1 = 0.f, a2 = 0.f;
#pragma unroll
    for (int g = 0; g < 8; ++g) { a1 += red[g * 32 + tid]; a2 += red[256 + g * 32 + tid]; }
    partials[(long)tid * nblk + blockIdx.x]        = a1;
    partials[(long)(32 + tid) * nblk + blockIdx.x] = a2;
  }
}

// ---------------- reduce partials -> stats[64] (sum[32], sumsq[32]) ----------------
__global__ __launch_bounds__(256) void k_reduce(const float* __restrict__ partials,
                                                int nblk, float* __restrict__ stats) {
  __shared__ float sd[256];
  int c = blockIdx.x;
  const float* p = partials + (long)c * nblk;
  float s = 0.f;
  for (int i = threadIdx.x; i < nblk; i += 256) s += p[i];
  sd[threadIdx.x] = s; __syncthreads();
  for (int st = 128; st > 0; st >>= 1) {
    if (threadIdx.x < st) sd[threadIdx.x] += sd[threadIdx.x + st];
    __syncthreads();
  }
  if (threadIdx.x == 0) stats[c] = sd[0];
}

// ---------------- BN apply, in place on out ----------------
__global__ __launch_bounds__(256) void k_bn(float* __restrict__ out,
                                            const float* __restrict__ stats,
                                            const float* __restrict__ gamma,
                                            const float* __restrict__ beta, int nf) {
  __shared__ float sc[32], sh[32];
  if (threadIdx.x < 32) {
    int o = threadIdx.x;
    float inv_n = 1.0f / (float)nf;
    float mean = stats[o] * inv_n;
    float var = stats[32 + o] * inv_n - mean * mean;
    float rstd = rsqrtf(var + 1e-5f);
    float g = gamma[o] * rstd;
    sc[o] = g;
    sh[o] = beta[o] - mean * g;
  }
  __syncthreads();
  long total4 = (long)nf * 8;
  long idx0 = (long)blockIdx.x * 256 + threadIdx.x;
  int ob = ((int)idx0 & 7) * 4;           // constant per thread (stride % 8 == 0)
  fv4 scv = *(const fv4*)&sc[ob];
  fv4 shv = *(const fv4*)&sh[ob];
  for (long idx = idx0; idx < total4; idx += (long)gridDim.x * 256) {
    fv4 v = *((const fv4*)out + idx);
    v = v * scv + shv;
    *((fv4*)out + idx) = v;
  }
}

extern "C" void kernel_launch(void* const* d_in, const int* in_sizes, int n_in,
                              void* d_out, int out_size, void* d_ws, size_t ws_size,
                              hipStream_t stream) {
  const float* x     = (const float*)d_in[0];
  const float* bary  = (const float*)d_in[1];
  const int*   numt  = (const int*)d_in[2];
  const float* W     = (const float*)d_in[3];
  const float* bias  = (const float*)d_in[4];
  const float* gamma = (const float*)d_in[5];
  const float* beta  = (const float*)d_in[6];
  float* out = (float*)d_out;

  const int nf   = in_sizes[2];
  const int nblk = (nf + FPB - 1) / FPB;
  const int nbS  = (nf + SCHUNK - 1) / SCHUNK;

  char* w = (char*)d_ws;
  int* offsets = (int*)w;
  size_t off1 = (4UL * (size_t)(nf + 1) + 255) & ~255UL;
  int* bsum = (int*)(w + off1);
  size_t off2 = (off1 + 4UL * (size_t)nbS + 255) & ~255UL;
  float* partials = (float*)(w + off2);
  size_t off3 = (off2 + 4UL * 64UL * (size_t)nblk + 255) & ~255UL;
  float* stats = (float*)(w + off3);

  scan1<<<nbS, 256, 0, stream>>>(numt, nf, bsum);
  scan2<<<1, 256, 0, stream>>>(bsum, nbS);
  scan3<<<nbS, 256, 0, stream>>>(numt, nf, bsum, offsets);
  k_main<<<nblk, 256, 0, stream>>>(x, bary, W, bias, offsets, out, partials, nf, nblk);
  k_reduce<<<64, 256, 0, stream>>>(partials, nblk, stats);
  k_bn<<<2048, 256, 0, stream>>>(out, stats, gamma, beta, nf);
}

// Round 6
// 112.708 us; speedup vs baseline: 2.0874x; 2.0874x over previous
//
#include <hip/hip_runtime.h>
#include <stdint.h>

typedef __attribute__((ext_vector_type(4))) float fv4;
typedef __attribute__((ext_vector_type(4))) short sv4;
typedef __attribute__((ext_vector_type(8))) short sv8;

#define SCHUNK 2048
#define FPB 128     // facets per block in k_main
#define PZB 108     // Z row pitch (shorts), R4-validated

static __device__ __forceinline__ short f2bf(float f) {
  union { float f; unsigned u; } v; v.f = f;
  unsigned u = v.u;
  u += 0x7fffu + ((u >> 16) & 1u);   // RNE to bf16
  return (short)(u >> 16);
}

// ---------------- scan: offsets from num_texture (R1-validated) ----------------
__global__ __launch_bounds__(256) void scan1(const int* __restrict__ num, int nf,
                                             int* __restrict__ bsum) {
  __shared__ int sd[256];
  int b = blockIdx.x, tid = threadIdx.x;
  int base = b * SCHUNK + tid * 8;
  int s = 0;
#pragma unroll
  for (int j = 0; j < 8; ++j) { int i = base + j; if (i < nf) s += num[i]; }
  sd[tid] = s; __syncthreads();
  for (int st = 128; st > 0; st >>= 1) {
    if (tid < st) sd[tid] += sd[tid + st];
    __syncthreads();
  }
  if (tid == 0) bsum[b] = sd[0];
}

__global__ __launch_bounds__(256) void scan2(int* __restrict__ bsum, int nb) {
  __shared__ int sd[256];
  int tid = threadIdx.x;
  int v = (tid < nb) ? bsum[tid] : 0;
  sd[tid] = v; __syncthreads();
  for (int off = 1; off < 256; off <<= 1) {
    int t = (tid >= off) ? sd[tid - off] : 0;
    __syncthreads();
    sd[tid] += t;
    __syncthreads();
  }
  if (tid < nb) bsum[tid] = sd[tid] - v;   // exclusive prefix
}

__global__ __launch_bounds__(256) void scan3(const int* __restrict__ num, int nf,
                                             const int* __restrict__ bsum,
                                             int* __restrict__ offsets) {
  __shared__ int sc_[256];
  int b = blockIdx.x, tid = threadIdx.x;
  int base = b * SCHUNK + tid * 8;
  int loc[8]; int s = 0;
#pragma unroll
  for (int j = 0; j < 8; ++j) {
    loc[j] = (base + j < nf) ? num[base + j] : 0;
    s += loc[j];
  }
  sc_[tid] = s; __syncthreads();
  for (int off = 1; off < 256; off <<= 1) {
    int t = (tid >= off) ? sc_[tid - off] : 0;
    __syncthreads();
    sc_[tid] += t;
    __syncthreads();
  }
  int run = bsum[b] + sc_[tid] - s;
#pragma unroll
  for (int j = 0; j < 8; ++j) {
    if (base + j < nf) offsets[base + j] = run;
    run += loc[j];
  }
  if (b == gridDim.x - 1 && tid == 255) offsets[nf] = run;
}

// ---------------- main: register fold -> Z(LDS) -> GEMM -> avg+bias+relu + stats ----------------
// Z[f, k*32+c] = sum_{s in facet f} x[s,c]*b[s,k]   (fp32 regs, stored bf16)
// out[f,o] = relu( (1/n_f) * sum_{ck} Z[f,ck]*W2[o,ck] + bias[o] )
__global__ __launch_bounds__(256) void k_main(
    const float* __restrict__ x, const float* __restrict__ bary,
    const float* __restrict__ W, const float* __restrict__ bias,
    const int* __restrict__ offsets, float* __restrict__ out,
    float* __restrict__ partials, int nf, int nblk)
{
  __shared__ short Z[FPB * PZB];       // 27648 B; aliased as float yt[128*33] after GEMM
  __shared__ short W2[32 * PZB];       // 6912 B; aliased as float red[512] at finalize
  __shared__ int off_s[FPB + 1];

  const int tid = threadIdx.x;
  const int f0 = blockIdx.x * FPB;

  // stage W2[o*PZB + k*32 + c] = bf16(W[o*96 + c*3 + k])   (R1-validated)
  for (int idx = tid; idx < 3072; idx += 256) {
    int o = idx / 96;
    int ck = idx - o * 96;
    int k = ck >> 5, c = ck & 31;
    W2[o * PZB + ck] = f2bf(W[o * 96 + c * 3 + k]);
  }
  for (int i = tid; i < FPB + 1; i += 256) {
    int f = f0 + i; if (f > nf) f = nf;
    off_s[i] = offsets[f];
  }
  __syncthreads();

  // ---- register fold: one thread per (facet, 16-channel half) ----
  {
    const int fl = tid >> 1;           // 0..127
    const int cb = (tid & 1) * 16;     // channel base: 0 or 16
    const int st = off_s[fl], en = off_s[fl + 1];

    float z0[16], z1[16], z2[16];
#pragma unroll
    for (int j = 0; j < 16; ++j) { z0[j] = 0.f; z1[j] = 0.f; z2[j] = 0.f; }

    if (en - st == 3) {
      // fast path: all loads issued up-front, fully independent
      fv4 xs[3][4];
      float bb[3][3];
#pragma unroll
      for (int s = 0; s < 3; ++s) {
        const float* xp = x + (size_t)(st + s) * 32 + cb;
#pragma unroll
        for (int q = 0; q < 4; ++q) xs[s][q] = *(const fv4*)(xp + 4 * q);
      }
#pragma unroll
      for (int s = 0; s < 3; ++s) {
        const float* bp = bary + (size_t)(st + s) * 3;
        bb[s][0] = bp[0]; bb[s][1] = bp[1]; bb[s][2] = bp[2];
      }
#pragma unroll
      for (int s = 0; s < 3; ++s)
#pragma unroll
        for (int q = 0; q < 4; ++q)
#pragma unroll
          for (int j = 0; j < 4; ++j) {
            float xv = xs[s][q][j];
            z0[q * 4 + j] += xv * bb[s][0];
            z1[q * 4 + j] += xv * bb[s][1];
            z2[q * 4 + j] += xv * bb[s][2];
          }
    } else {
      // generic ragged path
      for (int t = st; t < en; ++t) {
        const float* xp = x + (size_t)t * 32 + cb;
        fv4 xa = *(const fv4*)(xp);
        fv4 xb = *(const fv4*)(xp + 4);
        fv4 xc = *(const fv4*)(xp + 8);
        fv4 xd = *(const fv4*)(xp + 12);
        const float* bp = bary + (size_t)t * 3;
        float b0 = bp[0], b1 = bp[1], b2 = bp[2];
#pragma unroll
        for (int j = 0; j < 4; ++j) {
          z0[j]      += xa[j] * b0; z1[j]      += xa[j] * b1; z2[j]      += xa[j] * b2;
          z0[4 + j]  += xb[j] * b0; z1[4 + j]  += xb[j] * b1; z2[4 + j]  += xb[j] * b2;
          z0[8 + j]  += xc[j] * b0; z1[8 + j]  += xc[j] * b1; z2[8 + j]  += xc[j] * b2;
          z0[12 + j] += xd[j] * b0; z1[12 + j] += xd[j] * b1; z2[12 + j] += xd[j] * b2;
        }
      }
    }

    // write Z row segment: [fl][k*32 + cb .. +16) for k=0,1,2
    short* zr = &Z[fl * PZB + cb];
#pragma unroll
    for (int g = 0; g < 4; ++g) {
      sv4 p0, p1, p2;
#pragma unroll
      for (int j = 0; j < 4; ++j) {
        p0[j] = f2bf(z0[g * 4 + j]);
        p1[j] = f2bf(z1[g * 4 + j]);
        p2[j] = f2bf(z2[g * 4 + j]);
      }
      *(sv4*)(zr + g * 4)      = p0;
      *(sv4*)(zr + 32 + g * 4) = p1;
      *(sv4*)(zr + 64 + g * 4) = p2;
    }
  }
  __syncthreads();

  // ---- GEMM: M=128 (facets), N=32, K=96; 4 waves x 2 M-tiles x 2 N-tiles (R4-validated) ----
  const int lane = tid & 63;
  const int wv = tid >> 6;
  const int rowl = lane & 15;
  const int grp = lane >> 4;

  fv4 acc[2][2];
#pragma unroll
  for (int m = 0; m < 2; ++m)
#pragma unroll
    for (int n = 0; n < 2; ++n)
      acc[m][n] = (fv4){0.f, 0.f, 0.f, 0.f};

#pragma unroll
  for (int kb = 0; kb < 3; ++kb) {
    const int cko = kb * 32 + grp * 4;
    sv8 bfr[2];
#pragma unroll
    for (int n = 0; n < 2; ++n) {
      const short* wr = &W2[(n * 16 + rowl) * PZB + cko];
      sv4 lo = *(const sv4*)(wr);
      sv4 hi = *(const sv4*)(wr + 16);
#pragma unroll
      for (int j = 0; j < 4; ++j) { bfr[n][j] = lo[j]; bfr[n][4 + j] = hi[j]; }
    }
#pragma unroll
    for (int m = 0; m < 2; ++m) {
      const short* zr = &Z[(wv * 32 + m * 16 + rowl) * PZB + cko];
      sv4 lo = *(const sv4*)(zr);
      sv4 hi = *(const sv4*)(zr + 16);
      sv8 afr;
#pragma unroll
      for (int j = 0; j < 4; ++j) { afr[j] = lo[j]; afr[4 + j] = hi[j]; }
      acc[m][0] = __builtin_amdgcn_mfma_f32_16x16x32_bf16(afr, bfr[0], acc[m][0], 0, 0, 0);
      acc[m][1] = __builtin_amdgcn_mfma_f32_16x16x32_bf16(afr, bfr[1], acc[m][1], 0, 0, 0);
    }
  }
  __syncthreads();              // all Z reads done; safe to alias as yt

  // ---- y-tile to LDS with R4-validated C-write formula ----
  float* yt = (float*)Z;        // 128 x 33 floats = 16896 B
#pragma unroll
  for (int m = 0; m < 2; ++m)
#pragma unroll
    for (int n = 0; n < 2; ++n)
#pragma unroll
      for (int r = 0; r < 4; ++r)
        yt[(wv * 32 + m * 16 + grp * 4 + r) * 33 + n * 16 + rowl] = acc[m][n][r];
  __syncthreads();

  // ---- finalize with R4-validated pattern: avg + bias + relu, out, stats ----
  const int o_ep = tid & 31;
  const int g_ep = tid >> 5;
  float bo = bias[o_ep];
  float s1 = 0.f, s2 = 0.f;
#pragma unroll
  for (int i = 0; i < 16; ++i) {
    int fl = i * 8 + g_ep;
    int f = f0 + fl;
    if (f < nf) {
      int nm = off_s[fl + 1] - off_s[fl];
      float v = yt[fl * 33 + o_ep] / (float)(nm > 1 ? nm : 1) + bo;
      v = fmaxf(v, 0.f);
      out[f * 32 + o_ep] = v;
      s1 += v; s2 += v * v;
    }
  }
  __syncthreads();              // W2 reads long done; safe to alias as red
  float* red = (float*)W2;      // 512 floats = 2048 B
  red[tid] = s1;
  red[256 + tid] = s2;
  __syncthreads();
  if (tid < 32) {
    float a1 = 0.f, a2 = 0.f;
#pragma unroll
    for (int g = 0; g < 8; ++g) { a1 += red[g * 32 + tid]; a2 += red[256 + g * 32 + tid]; }
    partials[(long)tid * nblk + blockIdx.x]        = a1;
    partials[(long)(32 + tid) * nblk + blockIdx.x] = a2;
  }
}

// ---------------- reduce partials -> stats[64] (sum[32], sumsq[32]) ----------------
__global__ __launch_bounds__(256) void k_reduce(const float* __restrict__ partials,
                                                int nblk, float* __restrict__ stats) {
  __shared__ float sd[256];
  int c = blockIdx.x;
  const float* p = partials + (long)c * nblk;
  float s = 0.f;
  for (int i = threadIdx.x; i < nblk; i += 256) s += p[i];
  sd[threadIdx.x] = s; __syncthreads();
  for (int st = 128; st > 0; st >>= 1) {
    if (threadIdx.x < st) sd[threadIdx.x] += sd[threadIdx.x + st];
    __syncthreads();
  }
  if (threadIdx.x == 0) stats[c] = sd[0];
}

// ---------------- BN apply, in place on out ----------------
__global__ __launch_bounds__(256) void k_bn(float* __restrict__ out,
                                            const float* __restrict__ stats,
                                            const float* __restrict__ gamma,
                                            const float* __restrict__ beta, int nf) {
  __shared__ float sc[32], sh[32];
  if (threadIdx.x < 32) {
    int o = threadIdx.x;
    float inv_n = 1.0f / (float)nf;
    float mean = stats[o] * inv_n;
    float var = stats[32 + o] * inv_n - mean * mean;
    float rstd = rsqrtf(var + 1e-5f);
    float g = gamma[o] * rstd;
    sc[o] = g;
    sh[o] = beta[o] - mean * g;
  }
  __syncthreads();
  long total4 = (long)nf * 8;
  long idx0 = (long)blockIdx.x * 256 + threadIdx.x;
  int ob = ((int)idx0 & 7) * 4;           // constant per thread (stride % 8 == 0)
  fv4 scv = *(const fv4*)&sc[ob];
  fv4 shv = *(const fv4*)&sh[ob];
  for (long idx = idx0; idx < total4; idx += (long)gridDim.x * 256) {
    fv4 v = *((const fv4*)out + idx);
    v = v * scv + shv;
    *((fv4*)out + idx) = v;
  }
}

extern "C" void kernel_launch(void* const* d_in, const int* in_sizes, int n_in,
                              void* d_out, int out_size, void* d_ws, size_t ws_size,
                              hipStream_t stream) {
  const float* x     = (const float*)d_in[0];
  const float* bary  = (const float*)d_in[1];
  const int*   numt  = (const int*)d_in[2];
  const float* W     = (const float*)d_in[3];
  const float* bias  = (const float*)d_in[4];
  const float* gamma = (const float*)d_in[5];
  const float* beta  = (const float*)d_in[6];
  float* out = (float*)d_out;

  const int nf   = in_sizes[2];
  const int nblk = (nf + FPB - 1) / FPB;
  const int nbS  = (nf + SCHUNK - 1) / SCHUNK;

  char* w = (char*)d_ws;
  int* offsets = (int*)w;
  size_t off1 = (4UL * (size_t)(nf + 1) + 255) & ~255UL;
  int* bsum = (int*)(w + off1);
  size_t off2 = (off1 + 4UL * (size_t)nbS + 255) & ~255UL;
  float* partials = (float*)(w + off2);
  size_t off3 = (off2 + 4UL * 64UL * (size_t)nblk + 255) & ~255UL;
  float* stats = (float*)(w + off3);

  scan1<<<nbS, 256, 0, stream>>>(numt, nf, bsum);
  scan2<<<1, 256, 0, stream>>>(bsum, nbS);
  scan3<<<nbS, 256, 0, stream>>>(numt, nf, bsum, offsets);
  k_main<<<nblk, 256, 0, stream>>>(x, bary, W, bias, offsets, out, partials, nf, nblk);
  k_reduce<<<64, 256, 0, stream>>>(partials, nblk, stats);
  k_bn<<<2048, 256, 0, stream>>>(out, stats, gamma, beta, nf);
}

// Round 7
// 109.775 us; speedup vs baseline: 2.1431x; 1.0267x over previous
//
#include <hip/hip_runtime.h>
#include <hip/hip_bf16.h>
#include <stdint.h>

typedef __attribute__((ext_vector_type(4))) float fv4;
typedef __attribute__((ext_vector_type(4))) short sv4;
typedef __attribute__((ext_vector_type(8))) short sv8;

#define SCHUNK 2048
#define FPB 64      // facets per block in k_main
#define PZB 108     // Z row pitch (shorts), R4/R5-validated

static __device__ __forceinline__ short f2bf(float f) {
  __hip_bfloat16 h = __float2bfloat16(f);   // HW v_cvt, RNE
  union { __hip_bfloat16 h; short s; } u; u.h = h;
  return u.s;
}

// ---------------- scan: offsets from num_texture (R1-validated) ----------------
__global__ __launch_bounds__(256) void scan1(const int* __restrict__ num, int nf,
                                             int* __restrict__ bsum) {
  __shared__ int sd[256];
  int b = blockIdx.x, tid = threadIdx.x;
  int base = b * SCHUNK + tid * 8;
  int s = 0;
#pragma unroll
  for (int j = 0; j < 8; ++j) { int i = base + j; if (i < nf) s += num[i]; }
  sd[tid] = s; __syncthreads();
  for (int st = 128; st > 0; st >>= 1) {
    if (tid < st) sd[tid] += sd[tid + st];
    __syncthreads();
  }
  if (tid == 0) bsum[b] = sd[0];
}

__global__ __launch_bounds__(256) void scan2(int* __restrict__ bsum, int nb) {
  __shared__ int sd[256];
  int tid = threadIdx.x;
  int v = (tid < nb) ? bsum[tid] : 0;
  sd[tid] = v; __syncthreads();
  for (int off = 1; off < 256; off <<= 1) {
    int t = (tid >= off) ? sd[tid - off] : 0;
    __syncthreads();
    sd[tid] += t;
    __syncthreads();
  }
  if (tid < nb) bsum[tid] = sd[tid] - v;   // exclusive prefix
}

__global__ __launch_bounds__(256) void scan3(const int* __restrict__ num, int nf,
                                             const int* __restrict__ bsum,
                                             int* __restrict__ offsets) {
  __shared__ int sc_[256];
  int b = blockIdx.x, tid = threadIdx.x;
  int base = b * SCHUNK + tid * 8;
  int loc[8]; int s = 0;
#pragma unroll
  for (int j = 0; j < 8; ++j) {
    loc[j] = (base + j < nf) ? num[base + j] : 0;
    s += loc[j];
  }
  sc_[tid] = s; __syncthreads();
  for (int off = 1; off < 256; off <<= 1) {
    int t = (tid >= off) ? sc_[tid - off] : 0;
    __syncthreads();
    sc_[tid] += t;
    __syncthreads();
  }
  int run = bsum[b] + sc_[tid] - s;
#pragma unroll
  for (int j = 0; j < 8; ++j) {
    if (base + j < nf) offsets[base + j] = run;
    run += loc[j];
  }
  if (b == gridDim.x - 1 && tid == 255) offsets[nf] = run;
}

// ---------------- main: register fold -> Z(LDS) -> GEMM -> avg+bias+relu + stats ----------------
// Z[f, k*32+c] = sum_{s in facet f} x[s,c]*b[s,k]   (fp32 regs, stored bf16)
// out[f,o] = relu( (1/n_f) * sum_{ck} Z[f,ck]*W2[o,ck] + bias[o] )
__global__ __launch_bounds__(256) void k_main(
    const float* __restrict__ x, const float* __restrict__ bary,
    const float* __restrict__ W, const float* __restrict__ bias,
    const int* __restrict__ offsets, float* __restrict__ out,
    float* __restrict__ partials, int nf, int nblk)
{
  __shared__ short Z[FPB * PZB];       // 13824 B; aliased as float yt[64*33] after GEMM
  __shared__ short W2[32 * PZB];       // 6912 B; aliased as float red[512] at finalize
  __shared__ int off_s[FPB + 1];

  const int tid = threadIdx.x;
  const int f0 = blockIdx.x * FPB;

  // stage W2[o*PZB + k*32 + c] = bf16(W[o*96 + c*3 + k])   (R1-validated)
  for (int idx = tid; idx < 3072; idx += 256) {
    int o = idx / 96;
    int ck = idx - o * 96;
    int k = ck >> 5, c = ck & 31;
    W2[o * PZB + ck] = f2bf(W[o * 96 + c * 3 + k]);
  }
  if (tid < FPB + 1) {
    int f = f0 + tid; if (f > nf) f = nf;
    off_s[tid] = offsets[f];
  }
  __syncthreads();

  // ---- register fold: one thread per (facet, 8-channel quarter) ----
  {
    const int fl = tid >> 2;           // 0..63
    const int cb = (tid & 3) * 8;      // channel base: 0,8,16,24
    const int st = off_s[fl], en = off_s[fl + 1];

    float z0[8], z1[8], z2[8];
#pragma unroll
    for (int j = 0; j < 8; ++j) { z0[j] = 0.f; z1[j] = 0.f; z2[j] = 0.f; }

    if (en - st == 3) {
      // fast path: all loads issued up-front, fully independent
      fv4 xs[3][2];
      float bb[3][3];
#pragma unroll
      for (int s = 0; s < 3; ++s) {
        const float* xp = x + (size_t)(st + s) * 32 + cb;
        xs[s][0] = *(const fv4*)(xp);
        xs[s][1] = *(const fv4*)(xp + 4);
      }
#pragma unroll
      for (int s = 0; s < 3; ++s) {
        const float* bp = bary + (size_t)(st + s) * 3;
        bb[s][0] = bp[0]; bb[s][1] = bp[1]; bb[s][2] = bp[2];
      }
#pragma unroll
      for (int s = 0; s < 3; ++s)
#pragma unroll
        for (int q = 0; q < 2; ++q)
#pragma unroll
          for (int j = 0; j < 4; ++j) {
            float xv = xs[s][q][j];
            z0[q * 4 + j] += xv * bb[s][0];
            z1[q * 4 + j] += xv * bb[s][1];
            z2[q * 4 + j] += xv * bb[s][2];
          }
    } else {
      // generic ragged path
      for (int t = st; t < en; ++t) {
        const float* xp = x + (size_t)t * 32 + cb;
        fv4 xa = *(const fv4*)(xp);
        fv4 xb = *(const fv4*)(xp + 4);
        const float* bp = bary + (size_t)t * 3;
        float b0 = bp[0], b1 = bp[1], b2 = bp[2];
#pragma unroll
        for (int j = 0; j < 4; ++j) {
          z0[j]     += xa[j] * b0; z1[j]     += xa[j] * b1; z2[j]     += xa[j] * b2;
          z0[4 + j] += xb[j] * b0; z1[4 + j] += xb[j] * b1; z2[4 + j] += xb[j] * b2;
        }
      }
    }

    // write Z row segment: [fl][k*32 + cb .. +8) for k=0,1,2
    short* zr = &Z[fl * PZB + cb];
#pragma unroll
    for (int g = 0; g < 2; ++g) {
      sv4 p0, p1, p2;
#pragma unroll
      for (int j = 0; j < 4; ++j) {
        p0[j] = f2bf(z0[g * 4 + j]);
        p1[j] = f2bf(z1[g * 4 + j]);
        p2[j] = f2bf(z2[g * 4 + j]);
      }
      *(sv4*)(zr + g * 4)      = p0;
      *(sv4*)(zr + 32 + g * 4) = p1;
      *(sv4*)(zr + 64 + g * 4) = p2;
    }
  }
  __syncthreads();

  // ---- GEMM: M=64 (facets), N=32, K=96; 4 waves x 1 M-tile x 2 N-tiles (R5-validated) ----
  const int lane = tid & 63;
  const int wv = tid >> 6;
  const int rowl = lane & 15;
  const int grp = lane >> 4;

  fv4 acc[2];
  acc[0] = (fv4){0.f, 0.f, 0.f, 0.f};
  acc[1] = (fv4){0.f, 0.f, 0.f, 0.f};

#pragma unroll
  for (int kb = 0; kb < 3; ++kb) {
    const int cko = kb * 32 + grp * 4;
    sv8 bfr[2];
#pragma unroll
    for (int n = 0; n < 2; ++n) {
      const short* wr = &W2[(n * 16 + rowl) * PZB + cko];
      sv4 lo = *(const sv4*)(wr);
      sv4 hi = *(const sv4*)(wr + 16);
#pragma unroll
      for (int j = 0; j < 4; ++j) { bfr[n][j] = lo[j]; bfr[n][4 + j] = hi[j]; }
    }
    const short* zr = &Z[(wv * 16 + rowl) * PZB + cko];
    sv4 lo = *(const sv4*)(zr);
    sv4 hi = *(const sv4*)(zr + 16);
    sv8 afr;
#pragma unroll
    for (int j = 0; j < 4; ++j) { afr[j] = lo[j]; afr[4 + j] = hi[j]; }
    acc[0] = __builtin_amdgcn_mfma_f32_16x16x32_bf16(afr, bfr[0], acc[0], 0, 0, 0);
    acc[1] = __builtin_amdgcn_mfma_f32_16x16x32_bf16(afr, bfr[1], acc[1], 0, 0, 0);
  }
  __syncthreads();              // all Z reads done; safe to alias as yt

  // ---- y-tile to LDS with R5-validated C-write formula ----
  float* yt = (float*)Z;        // 64 x 33 floats = 8448 B
#pragma unroll
  for (int n = 0; n < 2; ++n)
#pragma unroll
    for (int r = 0; r < 4; ++r)
      yt[(wv * 16 + grp * 4 + r) * 33 + n * 16 + rowl] = acc[n][r];
  __syncthreads();

  // ---- finalize with R5-validated pattern: avg + bias + relu, out, stats ----
  const int o_ep = tid & 31;
  const int g_ep = tid >> 5;
  float bo = bias[o_ep];
  float s1 = 0.f, s2 = 0.f;
#pragma unroll
  for (int i = 0; i < 8; ++i) {
    int fl = i * 8 + g_ep;
    int f = f0 + fl;
    if (f < nf) {
      int nm = off_s[fl + 1] - off_s[fl];
      float v = yt[fl * 33 + o_ep] / (float)(nm > 1 ? nm : 1) + bo;
      v = fmaxf(v, 0.f);
      out[f * 32 + o_ep] = v;
      s1 += v; s2 += v * v;
    }
  }
  __syncthreads();              // all W2/yt reads done; safe to alias red
  float* red = (float*)W2;      // 512 floats = 2048 B
  red[tid] = s1;
  red[256 + tid] = s2;
  __syncthreads();
  if (tid < 32) {
    float a1 = 0.f, a2 = 0.f;
#pragma unroll
    for (int g = 0; g < 8; ++g) { a1 += red[g * 32 + tid]; a2 += red[256 + g * 32 + tid]; }
    partials[(long)tid * nblk + blockIdx.x]        = a1;
    partials[(long)(32 + tid) * nblk + blockIdx.x] = a2;
  }
}

// ---------------- reduce partials -> stats[64] (sum[32], sumsq[32]) ----------------
__global__ __launch_bounds__(256) void k_reduce(const float* __restrict__ partials,
                                                int nblk, float* __restrict__ stats) {
  __shared__ float sd[256];
  int c = blockIdx.x;
  const float* p = partials + (long)c * nblk;
  float s = 0.f;
  for (int i = threadIdx.x; i < nblk; i += 256) s += p[i];
  sd[threadIdx.x] = s; __syncthreads();
  for (int st = 128; st > 0; st >>= 1) {
    if (threadIdx.x < st) sd[threadIdx.x] += sd[threadIdx.x + st];
    __syncthreads();
  }
  if (threadIdx.x == 0) stats[c] = sd[0];
}

// ---------------- BN apply, in place on out ----------------
__global__ __launch_bounds__(256) void k_bn(float* __restrict__ out,
                                            const float* __restrict__ stats,
                                            const float* __restrict__ gamma,
                                            const float* __restrict__ beta, int nf) {
  __shared__ float sc[32], sh[32];
  if (threadIdx.x < 32) {
    int o = threadIdx.x;
    float inv_n = 1.0f / (float)nf;
    float mean = stats[o] * inv_n;
    float var = stats[32 + o] * inv_n - mean * mean;
    float rstd = rsqrtf(var + 1e-5f);
    float g = gamma[o] * rstd;
    sc[o] = g;
    sh[o] = beta[o] - mean * g;
  }
  __syncthreads();
  long total4 = (long)nf * 8;
  long idx0 = (long)blockIdx.x * 256 + threadIdx.x;
  int ob = ((int)idx0 & 7) * 4;           // constant per thread (stride % 8 == 0)
  fv4 scv = *(const fv4*)&sc[ob];
  fv4 shv = *(const fv4*)&sh[ob];
  for (long idx = idx0; idx < total4; idx += (long)gridDim.x * 256) {
    fv4 v = *((const fv4*)out + idx);
    v = v * scv + shv;
    *((fv4*)out + idx) = v;
  }
}

extern "C" void kernel_launch(void* const* d_in, const int* in_sizes, int n_in,
                              void* d_out, int out_size, void* d_ws, size_t ws_size,
                              hipStream_t stream) {
  const float* x     = (const float*)d_in[0];
  const float* bary  = (const float*)d_in[1];
  const int*   numt  = (const int*)d_in[2];
  const float* W     = (const float*)d_in[3];
  const float* bias  = (const float*)d_in[4];
  const float* gamma = (const float*)d_in[5];
  const float* beta  = (const float*)d_in[6];
  float* out = (float*)d_out;

  const int nf   = in_sizes[2];
  const int nblk = (nf + FPB - 1) / FPB;
  const int nbS  = (nf + SCHUNK - 1) / SCHUNK;

  char* w = (char*)d_ws;
  int* offsets = (int*)w;
  size_t off1 = (4UL * (size_t)(nf + 1) + 255) & ~255UL;
  int* bsum = (int*)(w + off1);
  size_t off2 = (off1 + 4UL * (size_t)nbS + 255) & ~255UL;
  float* partials = (float*)(w + off2);
  size_t off3 = (off2 + 4UL * 64UL * (size_t)nblk + 255) & ~255UL;
  float* stats = (float*)(w + off3);

  scan1<<<nbS, 256, 0, stream>>>(numt, nf, bsum);
  scan2<<<1, 256, 0, stream>>>(bsum, nbS);
  scan3<<<nbS, 256, 0, stream>>>(numt, nf, bsum, offsets);
  k_main<<<nblk, 256, 0, stream>>>(x, bary, W, bias, offsets, out, partials, nf, nblk);
  k_reduce<<<64, 256, 0, stream>>>(partials, nblk, stats);
  k_bn<<<2048, 256, 0, stream>>>(out, stats, gamma, beta, nf);
}